// Round 7
// baseline (303.692 us; speedup 1.0000x reference)
//
#include <hip/hip_runtime.h>
#include <hip/hip_bf16.h>

#define D_R 128
#define D_H 96
#define D_IN 224   // D_R + D_H
#define D_OUT 96
#define CAP 64     // bucket slots per node; deg ~ Poisson(8), P(>=64) ~ 1e-38
#define MPAD 104   // LDS msg row stride in bf16 (208 B: 16B-aligned rows, <=2-way bank alias)
#define NW 21504   // D_OUT * D_IN

typedef __attribute__((ext_vector_type(8))) short short8;
typedef __attribute__((ext_vector_type(4))) float f32x4;

static __device__ inline unsigned short f2b(float x) {
    __hip_bfloat16 b = __float2bfloat16(x);
    unsigned short u;
    __builtin_memcpy(&u, &b, 2);
    return u;
}

// -------- init: zero deg + convert W fp32->bf16 (one kernel, two ranges) ----
__global__ __launch_bounds__(256) void init_kernel(
    int* __restrict__ deg, int n_nodes,
    const float* __restrict__ W, unsigned short* __restrict__ W16)
{
    int i = blockIdx.x * 256 + threadIdx.x;
    if (i < n_nodes) deg[i] = 0;
    if (i < NW) W16[i] = f2b(W[i]);
}

// -------- single-pass bucket build (count+alloc+fill merged) ----------------
__global__ __launch_bounds__(256) void build_kernel(
    const int* __restrict__ nbrs, int* __restrict__ deg,
    int* __restrict__ bucket, int n_edges)
{
    int k = blockIdx.x * 256 + threadIdx.x;
    int e0 = 2 * k;
    if (e0 >= n_edges) return;
    if (e0 + 1 < n_edges) {
        int4 q = *reinterpret_cast<const int4*>(nbrs + 2 * e0);
        int p0 = atomicAdd(&deg[q.x], 1);
        if (p0 < CAP) bucket[(size_t)q.x * CAP + p0] = e0;
        int p1 = atomicAdd(&deg[q.z], 1);
        if (p1 < CAP) bucket[(size_t)q.z * CAP + p1] = e0 + 1;
    } else {
        int d = nbrs[2 * e0];
        int p0 = atomicAdd(&deg[d], 1);
        if (p0 < CAP) bucket[(size_t)d * CAP + p0] = e0;
    }
}

// -------- fused gather + MFMA GEMM ------------------------------------------
// Block = 256 threads (4 waves), owns 128 nodes.
// Phase A (gather): 2 threads per node; thread (node_local = t>>1, half = t&1)
//   accumulates features [half*48, half*48+48) over the node's bucket edges in
//   12 f32x4 registers (12 independent 16B h-loads per edge), then writes the
//   bf16 row into LDS msg tile [128][MPAD].
// Phase B (GEMM): out = relu([r | msg] @ W^T). A(r) from global (fp32->bf16
//   in-register), A(msg) from the LDS tile, B from L2-resident W16 (43 KB).
__global__ __launch_bounds__(256) void fused_kernel(
    const float* __restrict__ r, const float* __restrict__ h,
    const int* __restrict__ deg_arr, const int* __restrict__ bucket,
    const unsigned short* __restrict__ W16, float* __restrict__ out,
    int n_nodes)
{
    __shared__ unsigned short msg_lds[128 * MPAD];   // 26624 B

    // ---- phase A: gather ----
    {
        const int node_local = threadIdx.x >> 1;
        const int half = threadIdx.x & 1;
        const int node = blockIdx.x * 128 + node_local;

        f32x4 g[12];
#pragma unroll
        for (int c = 0; c < 12; ++c) g[c] = (f32x4){0.f, 0.f, 0.f, 0.f};

        if (node < n_nodes) {
            int deg = deg_arr[node]; if (deg > CAP) deg = CAP;
            const int* brow = bucket + (size_t)node * CAP;
            for (int i = 0; i < deg; ++i) {
                int e = brow[i];
                const float* p = h + (size_t)e * D_H + half * 48;
#pragma unroll
                for (int c = 0; c < 12; ++c)
                    g[c] += __builtin_nontemporal_load(
                        reinterpret_cast<const f32x4*>(p + c * 4));
            }
        }
        unsigned short* mrow = &msg_lds[node_local * MPAD + half * 48];
#pragma unroll
        for (int c = 0; c < 12; ++c) {
            ushort4 o;
            o.x = f2b(g[c].x); o.y = f2b(g[c].y);
            o.z = f2b(g[c].z); o.w = f2b(g[c].w);
            *reinterpret_cast<ushort4*>(mrow + c * 4) = o;
        }
    }
    __syncthreads();

    // ---- phase B: GEMM ----
    const int lane = threadIdx.x & 63;
    const int wv   = threadIdx.x >> 6;      // 0..3
    const int cl   = lane & 15;
    const int kch  = (lane >> 4) * 8;

    const int rowbase = blockIdx.x * 128 + wv * 32;

    f32x4 acc[2][6];
#pragma unroll
    for (int mf = 0; mf < 2; ++mf)
#pragma unroll
        for (int nf = 0; nf < 6; ++nf) acc[mf][nf] = (f32x4){0.f, 0.f, 0.f, 0.f};

    int arow0 = rowbase + cl;       if (arow0 >= n_nodes) arow0 = n_nodes - 1;
    int arow1 = rowbase + 16 + cl;  if (arow1 >= n_nodes) arow1 = n_nodes - 1;

    const float* rb[2] = { r + (size_t)arow0 * D_R + kch,
                           r + (size_t)arow1 * D_R + kch };
    const int lrow0 = wv * 32 + cl;          // LDS msg rows for this wave
    const int lrow1 = wv * 32 + 16 + cl;

    // phase B1: k-steps 0..3 from r (fp32 -> bf16 in-register)
#pragma unroll
    for (int ks = 0; ks < 4; ++ks) {
        const int k0 = ks * 32;
        short8 a[2];
#pragma unroll
        for (int mf = 0; mf < 2; ++mf) {
            const f32x4 u = __builtin_nontemporal_load(
                reinterpret_cast<const f32x4*>(rb[mf] + k0));
            const f32x4 v = __builtin_nontemporal_load(
                reinterpret_cast<const f32x4*>(rb[mf] + k0 + 4));
            short8 tv;
            tv[0] = (short)f2b(u.x); tv[1] = (short)f2b(u.y);
            tv[2] = (short)f2b(u.z); tv[3] = (short)f2b(u.w);
            tv[4] = (short)f2b(v.x); tv[5] = (short)f2b(v.y);
            tv[6] = (short)f2b(v.z); tv[7] = (short)f2b(v.w);
            a[mf] = tv;
        }
#pragma unroll
        for (int nf = 0; nf < 6; ++nf) {
            const short8 b = *reinterpret_cast<const short8*>(
                &W16[(nf * 16 + cl) * D_IN + k0 + kch]);
            acc[0][nf] = __builtin_amdgcn_mfma_f32_16x16x32_bf16(a[0], b, acc[0][nf], 0, 0, 0);
            acc[1][nf] = __builtin_amdgcn_mfma_f32_16x16x32_bf16(a[1], b, acc[1][nf], 0, 0, 0);
        }
    }

    // phase B2: k-steps 4..6 from LDS msg tile
#pragma unroll
    for (int ks = 0; ks < 3; ++ks) {
        const int k0 = ks * 32;
        short8 a[2];
        a[0] = *reinterpret_cast<const short8*>(&msg_lds[lrow0 * MPAD + k0 + kch]);
        a[1] = *reinterpret_cast<const short8*>(&msg_lds[lrow1 * MPAD + k0 + kch]);
#pragma unroll
        for (int nf = 0; nf < 6; ++nf) {
            const short8 b = *reinterpret_cast<const short8*>(
                &W16[(nf * 16 + cl) * D_IN + D_R + k0 + kch]);
            acc[0][nf] = __builtin_amdgcn_mfma_f32_16x16x32_bf16(a[0], b, acc[0][nf], 0, 0, 0);
            acc[1][nf] = __builtin_amdgcn_mfma_f32_16x16x32_bf16(a[1], b, acc[1][nf], 0, 0, 0);
        }
    }

    // ---- epilogue: ReLU + nontemporal store ----
    const int g4 = (lane >> 4) * 4;
#pragma unroll
    for (int mf = 0; mf < 2; ++mf) {
#pragma unroll
        for (int q = 0; q < 4; ++q) {
            const int row = rowbase + mf * 16 + g4 + q;
            if (row < n_nodes) {
                float* op = out + (size_t)row * D_OUT + cl;
#pragma unroll
                for (int nf = 0; nf < 6; ++nf)
                    __builtin_nontemporal_store(fmaxf(acc[mf][nf][q], 0.f), op + nf * 16);
            }
        }
    }
}

extern "C" void kernel_launch(void* const* d_in, const int* in_sizes, int n_in,
                              void* d_out, int out_size, void* d_ws, size_t ws_size,
                              hipStream_t stream) {
    const float* r    = (const float*)d_in[0];
    const float* h    = (const float*)d_in[1];
    const int*   nbrs = (const int*)d_in[2];
    const float* W    = (const float*)d_in[3];
    float*       out  = (float*)d_out;

    const int n_nodes = in_sizes[0] / D_R;
    const int n_edges = in_sizes[2] / 2;

    // workspace layout
    char* ws = (char*)d_ws;
    int* deg    = (int*)ws;
    size_t off = (size_t)n_nodes * sizeof(int);
    int* bucket = (int*)(ws + off);  off += (size_t)n_nodes * CAP * sizeof(int);
    unsigned short* W16 = (unsigned short*)(ws + off);   // NW bf16

    const int pair_blocks = ((n_edges + 1) / 2 + 255) / 256;
    const int init_blocks = (n_nodes > NW ? n_nodes : NW) / 256 + 1;

    init_kernel<<<init_blocks, 256, 0, stream>>>(deg, n_nodes, W, W16);
    build_kernel<<<pair_blocks, 256, 0, stream>>>(nbrs, deg, bucket, n_edges);

    {
        dim3 grid((n_nodes + 127) / 128);
        fused_kernel<<<grid, 256, 0, stream>>>(r, h, deg, bucket, W16, out, n_nodes);
    }
}

// Round 8
// 164.372 us; speedup vs baseline: 1.8476x; 1.8476x over previous
//
#include <hip/hip_runtime.h>
#include <hip/hip_bf16.h>

#define D_R 128
#define D_H 96
#define D_IN 224   // D_R + D_H
#define D_OUT 96
#define CAP 64     // bucket slots per node; deg ~ Poisson(8), P(>=64) ~ 1e-38
#define NW 21504   // D_OUT * D_IN

typedef __attribute__((ext_vector_type(8))) short short8;
typedef __attribute__((ext_vector_type(4))) float f32x4;

static __device__ inline unsigned short f2b(float x) {
    __hip_bfloat16 b = __float2bfloat16(x);
    unsigned short u;
    __builtin_memcpy(&u, &b, 2);
    return u;
}

// -------- init: zero deg + convert W fp32->bf16 (one kernel, two ranges) ----
__global__ __launch_bounds__(256) void init_kernel(
    int* __restrict__ deg, int n_nodes,
    const float* __restrict__ W, unsigned short* __restrict__ W16)
{
    int i = blockIdx.x * 256 + threadIdx.x;
    if (i < n_nodes) deg[i] = 0;
    if (i < NW) W16[i] = f2b(W[i]);
}

// -------- single-pass bucket build (count+alloc+fill merged) ----------------
__global__ __launch_bounds__(256) void build_kernel(
    const int* __restrict__ nbrs, int* __restrict__ deg,
    int* __restrict__ bucket, int n_edges)
{
    int k = blockIdx.x * 256 + threadIdx.x;
    int e0 = 2 * k;
    if (e0 >= n_edges) return;
    if (e0 + 1 < n_edges) {
        int4 q = *reinterpret_cast<const int4*>(nbrs + 2 * e0);
        int p0 = atomicAdd(&deg[q.x], 1);
        if (p0 < CAP) bucket[(size_t)q.x * CAP + p0] = e0;
        int p1 = atomicAdd(&deg[q.z], 1);
        if (p1 < CAP) bucket[(size_t)q.z * CAP + p1] = e0 + 1;
    } else {
        int d = nbrs[2 * e0];
        int p0 = atomicAdd(&deg[d], 1);
        if (p0 < CAP) bucket[(size_t)d * CAP + p0] = e0;
    }
}

// ---------------- gather-sum (no atomics), bf16 output ----------------
// 24 threads per node; thread covers a float4 of the 96 features.
// int4 prefetch of 4 edge IDs -> 4 independent h loads in flight.
// (identical to the 160us round-6 version)
__global__ __launch_bounds__(256) void gather_kernel(
    const float* __restrict__ h, const int* __restrict__ deg_arr,
    const int* __restrict__ bucket, unsigned short* __restrict__ msg16,
    int n_nodes)
{
    int t = blockIdx.x * 256 + threadIdx.x;
    int node = t / 24;
    if (node >= n_nodes) return;
    int f4 = (t - node * 24) * 4;
    int deg = deg_arr[node]; if (deg > CAP) deg = CAP;
    const int* brow = bucket + (size_t)node * CAP;

    f32x4 a0 = (f32x4){0.f,0.f,0.f,0.f}, a1 = a0, a2 = a0, a3 = a0;
    int i = 0;
    for (; i + 4 <= deg; i += 4) {
        int4 e = *reinterpret_cast<const int4*>(brow + i);
        a0 += __builtin_nontemporal_load(
            reinterpret_cast<const f32x4*>(h + (size_t)e.x * D_H + f4));
        a1 += __builtin_nontemporal_load(
            reinterpret_cast<const f32x4*>(h + (size_t)e.y * D_H + f4));
        a2 += __builtin_nontemporal_load(
            reinterpret_cast<const f32x4*>(h + (size_t)e.z * D_H + f4));
        a3 += __builtin_nontemporal_load(
            reinterpret_cast<const f32x4*>(h + (size_t)e.w * D_H + f4));
    }
    for (; i < deg; ++i) {
        int e = brow[i];
        a0 += __builtin_nontemporal_load(
            reinterpret_cast<const f32x4*>(h + (size_t)e * D_H + f4));
    }
    f32x4 s = (a0 + a1) + (a2 + a3);
    ushort4 o;
    o.x = f2b(s.x); o.y = f2b(s.y); o.z = f2b(s.z); o.w = f2b(s.w);
    *reinterpret_cast<ushort4*>(msg16 + (size_t)node * D_H + f4) = o;
}

// -------- MFMA GEMM: out = relu([r | msg] @ W^T), bf16 inputs, f32 acc ----
// B fragments read directly from L2-resident W16 (42KB): no LDS, no barrier.
__global__ __launch_bounds__(256) void mfma_gemm_kernel(
    const float* __restrict__ r, const unsigned short* __restrict__ msg16,
    const unsigned short* __restrict__ W16, float* __restrict__ out, int n_nodes)
{
    const int lane = threadIdx.x & 63;
    const int wv   = threadIdx.x >> 6;      // 0..3
    const int cl   = lane & 15;
    const int kch  = (lane >> 4) * 8;

    const int rowbase = blockIdx.x * 128 + wv * 32;

    f32x4 acc[2][6];
#pragma unroll
    for (int mf = 0; mf < 2; ++mf)
#pragma unroll
        for (int nf = 0; nf < 6; ++nf) acc[mf][nf] = (f32x4){0.f, 0.f, 0.f, 0.f};

    int arow0 = rowbase + cl;       if (arow0 >= n_nodes) arow0 = n_nodes - 1;
    int arow1 = rowbase + 16 + cl;  if (arow1 >= n_nodes) arow1 = n_nodes - 1;

    const float* rb[2] = { r + (size_t)arow0 * D_R + kch,
                           r + (size_t)arow1 * D_R + kch };
    const unsigned short* mb[2] = { msg16 + (size_t)arow0 * D_H + kch,
                                    msg16 + (size_t)arow1 * D_H + kch };
    const unsigned short* wb = W16 + (size_t)cl * D_IN + kch;   // + nf*16*D_IN + k0

    // ---- phase 1: k-steps 0..3 from r (fp32 -> bf16 in-register) ----
#pragma unroll
    for (int ks = 0; ks < 4; ++ks) {
        const int k0 = ks * 32;
        short8 a[2];
#pragma unroll
        for (int mf = 0; mf < 2; ++mf) {
            const f32x4 u = __builtin_nontemporal_load(
                reinterpret_cast<const f32x4*>(rb[mf] + k0));
            const f32x4 v = __builtin_nontemporal_load(
                reinterpret_cast<const f32x4*>(rb[mf] + k0 + 4));
            short8 tv;
            tv[0] = (short)f2b(u.x); tv[1] = (short)f2b(u.y);
            tv[2] = (short)f2b(u.z); tv[3] = (short)f2b(u.w);
            tv[4] = (short)f2b(v.x); tv[5] = (short)f2b(v.y);
            tv[6] = (short)f2b(v.z); tv[7] = (short)f2b(v.w);
            a[mf] = tv;
        }
#pragma unroll
        for (int nf = 0; nf < 6; ++nf) {
            const short8 b = *reinterpret_cast<const short8*>(
                wb + (size_t)nf * 16 * D_IN + k0);
            acc[0][nf] = __builtin_amdgcn_mfma_f32_16x16x32_bf16(a[0], b, acc[0][nf], 0, 0, 0);
            acc[1][nf] = __builtin_amdgcn_mfma_f32_16x16x32_bf16(a[1], b, acc[1][nf], 0, 0, 0);
        }
    }

    // ---- phase 2: k-steps 4..6 from msg16 (already bf16) ----
#pragma unroll
    for (int ks = 0; ks < 3; ++ks) {
        const int k0 = ks * 32;
        short8 a[2];
        a[0] = *reinterpret_cast<const short8*>(mb[0] + k0);
        a[1] = *reinterpret_cast<const short8*>(mb[1] + k0);
#pragma unroll
        for (int nf = 0; nf < 6; ++nf) {
            const short8 b = *reinterpret_cast<const short8*>(
                wb + (size_t)nf * 16 * D_IN + D_R + k0);
            acc[0][nf] = __builtin_amdgcn_mfma_f32_16x16x32_bf16(a[0], b, acc[0][nf], 0, 0, 0);
            acc[1][nf] = __builtin_amdgcn_mfma_f32_16x16x32_bf16(a[1], b, acc[1][nf], 0, 0, 0);
        }
    }

    // ---- epilogue: ReLU + nontemporal store ----
    const int g4 = (lane >> 4) * 4;
#pragma unroll
    for (int mf = 0; mf < 2; ++mf) {
#pragma unroll
        for (int q = 0; q < 4; ++q) {
            const int row = rowbase + mf * 16 + g4 + q;
            if (row < n_nodes) {
                float* op = out + (size_t)row * D_OUT + cl;
#pragma unroll
                for (int nf = 0; nf < 6; ++nf)
                    __builtin_nontemporal_store(fmaxf(acc[mf][nf][q], 0.f), op + nf * 16);
            }
        }
    }
}

extern "C" void kernel_launch(void* const* d_in, const int* in_sizes, int n_in,
                              void* d_out, int out_size, void* d_ws, size_t ws_size,
                              hipStream_t stream) {
    const float* r    = (const float*)d_in[0];
    const float* h    = (const float*)d_in[1];
    const int*   nbrs = (const int*)d_in[2];
    const float* W    = (const float*)d_in[3];
    float*       out  = (float*)d_out;

    const int n_nodes = in_sizes[0] / D_R;
    const int n_edges = in_sizes[2] / 2;

    // workspace layout
    char* ws = (char*)d_ws;
    unsigned short* msg16 = (unsigned short*)ws;                       // n_nodes*D_H bf16
    size_t off = (size_t)n_nodes * D_H * sizeof(unsigned short);
    int* deg    = (int*)(ws + off);  off += (size_t)n_nodes * sizeof(int);
    int* bucket = (int*)(ws + off);  off += (size_t)n_nodes * CAP * sizeof(int);
    unsigned short* W16 = (unsigned short*)(ws + off);                 // NW bf16

    const int pair_blocks = ((n_edges + 1) / 2 + 255) / 256;
    const int init_blocks = (n_nodes > NW ? n_nodes : NW) / 256 + 1;

    init_kernel<<<init_blocks, 256, 0, stream>>>(deg, n_nodes, W, W16);
    build_kernel<<<pair_blocks, 256, 0, stream>>>(nbrs, deg, bucket, n_edges);

    {
        long long total = (long long)n_nodes * 24;
        int blocks = (int)((total + 255) / 256);
        gather_kernel<<<blocks, 256, 0, stream>>>(h, deg, bucket, msg16, n_nodes);
    }
    {
        dim3 grid((n_nodes + 127) / 128);
        mfma_gemm_kernel<<<grid, 256, 0, stream>>>(r, msg16, W16, out, n_nodes);
    }
}